// Round 2
// baseline (1141.063 us; speedup 1.0000x reference)
//
#include <hip/hip_runtime.h>
#include <stdint.h>

#define NTOK 4096
#define DDIM 2048
#define FDIM 5632
#define NEXP 8
#define RLORA 16
#define TWOF 11264
#define BCOLS 11520   // 2F + 2*E*R  (w1 | w3 | a1 | a3 rows)
#define PADROWS 10240 // 8192 pairs + worst-case 8*255 padding, 256-granular
#define LSCALE 2.0f

typedef __attribute__((ext_vector_type(4))) float f32x4;
typedef __attribute__((ext_vector_type(8))) short short8;
typedef unsigned short u16;

#define AS1 __attribute__((address_space(1)))
#define AS3 __attribute__((address_space(3)))

__device__ __forceinline__ float b2f(short s) {
  union { float f; unsigned u; } v;
  v.u = ((unsigned)(u16)s) << 16;
  return v.f;
}
__device__ __forceinline__ u16 f2b(float f) {
  union { float f; unsigned u; } v; v.f = f;
  unsigned r = v.u + 0x7fffu + ((v.u >> 16) & 1u);   // RNE bf16
  return (u16)(r >> 16);
}

// ---------------- cast f32 -> bf16, 4-wide ----------------
__global__ __launch_bounds__(256) void cast_kernel(const float* __restrict__ src, u16* __restrict__ dst, int n4) {
  int stride = gridDim.x * 256;
  for (int i = blockIdx.x * 256 + threadIdx.x; i < n4; i += stride) {
    float4 v = reinterpret_cast<const float4*>(src)[i];
    ushort4 o;
    o.x = f2b(v.x); o.y = f2b(v.y); o.z = f2b(v.z); o.w = f2b(v.w);
    reinterpret_cast<ushort4*>(dst)[i] = o;
  }
}

// ---------------- router: fp32 logits, top-2, softmax ----------------
__global__ __launch_bounds__(256) void router_kernel(const float* __restrict__ x, const float* __restrict__ gw,
                                                     int2* __restrict__ tok_e, float2* __restrict__ tok_w) {
  int tok = blockIdx.x;
  const float* xr = x + (size_t)tok * DDIM;
  float acc[NEXP];
#pragma unroll
  for (int e = 0; e < NEXP; ++e) acc[e] = 0.f;
  for (int d = threadIdx.x; d < DDIM; d += 256) {
    float xv = xr[d];
#pragma unroll
    for (int e = 0; e < NEXP; ++e) acc[e] += xv * gw[e * DDIM + d];
  }
#pragma unroll
  for (int e = 0; e < NEXP; ++e) {
#pragma unroll
    for (int off = 32; off > 0; off >>= 1) acc[e] += __shfl_down(acc[e], off);
  }
  __shared__ float red[4][NEXP];
  int wid = threadIdx.x >> 6;
  int lane = threadIdx.x & 63;
  if (lane == 0) {
#pragma unroll
    for (int e = 0; e < NEXP; ++e) red[wid][e] = acc[e];
  }
  __syncthreads();
  if (threadIdx.x == 0) {
    float l[NEXP];
#pragma unroll
    for (int e = 0; e < NEXP; ++e) l[e] = red[0][e] + red[1][e] + red[2][e] + red[3][e];
    int i0 = 0;
#pragma unroll
    for (int e = 1; e < NEXP; ++e) if (l[e] > l[i0]) i0 = e;   // strict >: first max (top_k tie rule)
    int i1 = (i0 == 0) ? 1 : 0;
#pragma unroll
    for (int e = 0; e < NEXP; ++e) if (e != i0 && e != i1 && l[e] > l[i1]) i1 = e;
    float ex = __expf(l[i1] - l[i0]);       // <= 1
    float w0 = 1.f / (1.f + ex);
    float w1v = ex / (1.f + ex);
    int2 ev; ev.x = i0; ev.y = i1;
    float2 wv; wv.x = w0; wv.y = w1v;
    tok_e[tok] = ev;
    tok_w[tok] = wv;
  }
}

// ---------------- bucket (token,slot) pairs by expert, 256-padded ----------------
__global__ __launch_bounds__(256) void build_pairs(const int2* __restrict__ tok_e, const float2* __restrict__ tok_w,
                                                   int* __restrict__ pair_tok, float* __restrict__ pair_w,
                                                   int* __restrict__ pair_k, int* __restrict__ poff) {
  __shared__ int cnt[NEXP];
  __shared__ int base[NEXP + 1];
  __shared__ int cur[NEXP];
  if (threadIdx.x < NEXP) cnt[threadIdx.x] = 0;
  __syncthreads();
  for (int t = threadIdx.x; t < NTOK; t += 256) {
    int2 ee = tok_e[t];
    atomicAdd(&cnt[ee.x], 1);
    atomicAdd(&cnt[ee.y], 1);
  }
  for (int i = threadIdx.x; i < PADROWS; i += 256) pair_tok[i] = -1;
  __syncthreads();
  if (threadIdx.x == 0) {
    int o = 0;
#pragma unroll
    for (int e = 0; e < NEXP; ++e) { base[e] = o; o += ((cnt[e] + 255) >> 8) << 8; }
    base[NEXP] = o;
  }
  __syncthreads();
  if (threadIdx.x < NEXP) cur[threadIdx.x] = base[threadIdx.x];
  __syncthreads();
  for (int t = threadIdx.x; t < NTOK; t += 256) {
    int2 ee = tok_e[t];
    float2 wv = tok_w[t];
    int s0 = atomicAdd(&cur[ee.x], 1);
    pair_tok[s0] = t; pair_w[s0] = wv.x; pair_k[s0] = 0;
    int s1 = atomicAdd(&cur[ee.y], 1);
    pair_tok[s1] = t; pair_w[s1] = wv.y; pair_k[s1] = 1;
  }
  __syncthreads();
  if (threadIdx.x <= NEXP) poff[threadIdx.x] = base[threadIdx.x];
}

// ================= 256x256 8-phase bf16 MFMA GEMM (T2-layout + T3/T4/T5) =================
// C = A(row-major [M][K]) * B(row-major [N][K])^T, 512 threads = 8 waves (2Mx4N),
// per-wave output 128x64 = acc[8][4]. LDS: [2 buf][2 khalf][256 rows][32 k] bf16 per
// operand = 128 KiB total. K-half layout makes ds_read_b128 bank-balanced (8 lanes per
// 4-bank span) without XOR swizzle, and staging units die exactly one group before reuse.

__device__ __forceinline__ void stage_unit(const u16* __restrict__ src, int ld, char* ldsbase, int tid) {
#pragma unroll
  for (int h = 0; h < 2; ++h) {
    int q = h * 512 + tid;            // 0..1023 16B chunks; 256 rows x 4 groups
    int r = q >> 2, g = q & 3;
    const char* s = (const char*)(src + (size_t)r * ld + g * 8);
    __builtin_amdgcn_global_load_lds((const AS1 void*)s, (AS3 void*)(ldsbase + q * 16), 16, 0, 0);
  }
}

#define GBAR()  { __builtin_amdgcn_s_barrier(); __builtin_amdgcn_sched_barrier(0); }

template<bool STG>
__device__ __forceinline__ void group4(const u16* __restrict__ An, const u16* __restrict__ Bn,
                                       int lda, int ldb,
                                       const char* Ard, const char* Brd, char* Awr, char* Bwr,
                                       int abase, int bbase, int tid, f32x4 (&acc)[8][4]) {
  short8 av[4], bv[4];
  // ---- phase 1: kh0, m-frags 0-3 + B n-frags 0-3; stage next B-kh0 ----
#pragma unroll
  for (int i = 0; i < 4; ++i) {
    av[i] = *(const short8*)(Ard + abase + i * 1024);
    bv[i] = *(const short8*)(Brd + bbase + i * 1024);
  }
  if (STG) stage_unit(Bn, ldb, Bwr, tid);
  GBAR();
  __builtin_amdgcn_s_setprio(1);
#pragma unroll
  for (int i = 0; i < 4; ++i)
#pragma unroll
    for (int j = 0; j < 4; ++j)
      acc[i][j] = __builtin_amdgcn_mfma_f32_16x16x32_bf16(av[i], bv[j], acc[i][j], 0, 0, 0);
  __builtin_amdgcn_s_setprio(0);
  GBAR();
  // ---- phase 2: kh0, m-frags 4-7 (reuse bv); stage next A-kh0; counted vmcnt ----
#pragma unroll
  for (int i = 0; i < 4; ++i)
    av[i] = *(const short8*)(Ard + abase + 4096 + i * 1024);
  if (STG) {
    stage_unit(An, lda, Awr, tid);
    asm volatile("s_waitcnt vmcnt(4)" ::: "memory");
    __builtin_amdgcn_sched_barrier(0);
  }
  GBAR();
  __builtin_amdgcn_s_setprio(1);
#pragma unroll
  for (int i = 0; i < 4; ++i)
#pragma unroll
    for (int j = 0; j < 4; ++j)
      acc[4 + i][j] = __builtin_amdgcn_mfma_f32_16x16x32_bf16(av[i], bv[j], acc[4 + i][j], 0, 0, 0);
  __builtin_amdgcn_s_setprio(0);
  GBAR();
  // ---- phase 3: kh1, m-frags 0-3 + B n-frags 0-3; stage next B-kh1 ----
#pragma unroll
  for (int i = 0; i < 4; ++i) {
    av[i] = *(const short8*)(Ard + 16384 + abase + i * 1024);
    bv[i] = *(const short8*)(Brd + 16384 + bbase + i * 1024);
  }
  if (STG) stage_unit(Bn + 32, ldb, Bwr + 16384, tid);
  GBAR();
  __builtin_amdgcn_s_setprio(1);
#pragma unroll
  for (int i = 0; i < 4; ++i)
#pragma unroll
    for (int j = 0; j < 4; ++j)
      acc[i][j] = __builtin_amdgcn_mfma_f32_16x16x32_bf16(av[i], bv[j], acc[i][j], 0, 0, 0);
  __builtin_amdgcn_s_setprio(0);
  GBAR();
  // ---- phase 4: kh1, m-frags 4-7; stage next A-kh1; counted vmcnt ----
#pragma unroll
  for (int i = 0; i < 4; ++i)
    av[i] = *(const short8*)(Ard + 16384 + abase + 4096 + i * 1024);
  if (STG) {
    stage_unit(An + 32, lda, Awr + 16384, tid);
    asm volatile("s_waitcnt vmcnt(4)" ::: "memory");
    __builtin_amdgcn_sched_barrier(0);
  }
  GBAR();
  __builtin_amdgcn_s_setprio(1);
#pragma unroll
  for (int i = 0; i < 4; ++i)
#pragma unroll
    for (int j = 0; j < 4; ++j)
      acc[4 + i][j] = __builtin_amdgcn_mfma_f32_16x16x32_bf16(av[i], bv[j], acc[4 + i][j], 0, 0, 0);
  __builtin_amdgcn_s_setprio(0);
  GBAR();
}

__device__ __forceinline__ void mm256(const u16* __restrict__ A, const u16* __restrict__ B,
                                      int lda, int ldb, int NT,
                                      char* lAb, char* lBb, f32x4 (&acc)[8][4]) {
  const int tid = threadIdx.x;
  const int lane = tid & 63, wid = tid >> 6;
  const int wr = wid >> 2, wc = wid & 3;
  const int lm = lane & 15, lg = lane >> 4;
  const int abase = wr * 128 * 64 + lm * 64 + lg * 16;   // byte offset of m-frag 0 within khalf
  const int bbase = wc * 64 * 64 + lm * 64 + lg * 16;
  // prologue: stage tile 0 (4 units) into buf 0, drain fully
  stage_unit(B, ldb, lBb, tid);
  stage_unit(A, lda, lAb, tid);
  stage_unit(B + 32, ldb, lBb + 16384, tid);
  stage_unit(A + 32, lda, lAb + 16384, tid);
  asm volatile("s_waitcnt vmcnt(0)" ::: "memory");
  GBAR();
  for (int t = 0; t < NT - 1; ++t) {
    int c = t & 1;
    group4<true>(A + (size_t)(t + 1) * 64, B + (size_t)(t + 1) * 64, lda, ldb,
                 (const char*)(lAb + c * 32768), (const char*)(lBb + c * 32768),
                 lAb + (c ^ 1) * 32768, lBb + (c ^ 1) * 32768, abase, bbase, tid, acc);
  }
  asm volatile("s_waitcnt vmcnt(0)" ::: "memory");
  GBAR();
  int c = (NT - 1) & 1;
  group4<false>(A, B, lda, ldb,
                (const char*)(lAb + c * 32768), (const char*)(lBb + c * 32768),
                lAb, lBb, abase, bbase, tid, acc);
}

// ---------------- GEMM1: base13_ext = x_bf16 @ [w1;w3;a1;a3]^T ----------------
__global__ __launch_bounds__(512, 2) void gemm_base(const u16* __restrict__ xb, const u16* __restrict__ Ball,
                                                    u16* __restrict__ base13) {
  __shared__ u16 lA[2 * 2 * 256 * 32];
  __shared__ u16 lB[2 * 2 * 256 * 32];
  // bijective XCD swizzle: nwg = 720 = 8*90
  int orig = blockIdx.x;
  int wgid = (orig & 7) * 90 + (orig >> 3);
  int mt = wgid / 45, nt = wgid % 45;
  int m0 = mt * 256, n0 = nt * 256;
  f32x4 acc[8][4];
  f32x4 z = {0.f, 0.f, 0.f, 0.f};
#pragma unroll
  for (int i = 0; i < 8; ++i)
#pragma unroll
    for (int j = 0; j < 4; ++j) acc[i][j] = z;
  mm256(xb + (size_t)m0 * DDIM, Ball + (size_t)n0 * DDIM, DDIM, DDIM, DDIM / 64,
        (char*)lA, (char*)lB, acc);
  const int tid = threadIdx.x;
  const int lane = tid & 63, wid = tid >> 6;
  const int wr = wid >> 2, wc = wid & 3;
  const int lm = lane & 15, lq = (lane >> 4) << 2;
#pragma unroll
  for (int m = 0; m < 8; ++m) {
#pragma unroll
    for (int n = 0; n < 4; ++n) {
      int col = n0 + wc * 64 + n * 16 + lm;
#pragma unroll
      for (int q = 0; q < 4; ++q) {
        int row = m0 + wr * 128 + m * 16 + lq + q;
        base13[(size_t)row * BCOLS + col] = f2b(acc[m][n][q]);
      }
    }
  }
}

// ---------------- act: SwiGLU with rank-16 LoRA on h1/h3 ----------------
__global__ __launch_bounds__(256) void act_kernel(const u16* __restrict__ base13,
                                                  const float* __restrict__ b1, const float* __restrict__ b3,
                                                  const int* __restrict__ pair_tok, const int* __restrict__ poff,
                                                  u16* __restrict__ act) {
  __shared__ float lb1[128 * 16];
  __shared__ float lb3[128 * 16];
  int f0 = blockIdx.x * 128;
  int r0 = blockIdx.y * 32;
  if (r0 >= poff[NEXP]) return;
  int e = 0;
  while (r0 >= poff[e + 1]) ++e;
  const float4* pb1 = reinterpret_cast<const float4*>(b1 + ((size_t)e * FDIM + f0) * RLORA);
  const float4* pb3 = reinterpret_cast<const float4*>(b3 + ((size_t)e * FDIM + f0) * RLORA);
  for (int i = threadIdx.x; i < 128 * 16 / 4; i += 256) {
    reinterpret_cast<float4*>(lb1)[i] = pb1[i];
    reinterpret_cast<float4*>(lb3)[i] = pb3[i];
  }
  __syncthreads();
  int pr = r0 + (threadIdx.x >> 3);
  int fg = (threadIdx.x & 7) << 4;
  int tok = pair_tok[pr];
  if (tok < 0) return;
  const u16* bp = base13 + (size_t)tok * BCOLS;
  short8 x1a = *(const short8*)(bp + TWOF + e * 16);
  short8 x1b = *(const short8*)(bp + TWOF + e * 16 + 8);
  short8 x3a = *(const short8*)(bp + TWOF + NEXP * RLORA + e * 16);
  short8 x3b = *(const short8*)(bp + TWOF + NEXP * RLORA + e * 16 + 8);
  float xa1[16], xa3[16];
#pragma unroll
  for (int r = 0; r < 8; ++r) {
    xa1[r] = b2f(x1a[r]); xa1[r + 8] = b2f(x1b[r]);
    xa3[r] = b2f(x3a[r]); xa3[r + 8] = b2f(x3b[r]);
  }
  short8 h1a = *(const short8*)(bp + f0 + fg);
  short8 h1b = *(const short8*)(bp + f0 + fg + 8);
  short8 h3a = *(const short8*)(bp + FDIM + f0 + fg);
  short8 h3b = *(const short8*)(bp + FDIM + f0 + fg + 8);
  short8 o0, o1;
#pragma unroll
  for (int ii = 0; ii < 16; ++ii) {
    float hb1 = b2f(ii < 8 ? h1a[ii] : h1b[ii - 8]);
    float hb3 = b2f(ii < 8 ? h3a[ii] : h3b[ii - 8]);
    const float4* l1 = reinterpret_cast<const float4*>(lb1 + (fg + ii) * 16);
    const float4* l3 = reinterpret_cast<const float4*>(lb3 + (fg + ii) * 16);
    float d1 = 0.f, d3 = 0.f;
#pragma unroll
    for (int c = 0; c < 4; ++c) {
      float4 v1 = l1[c], v3 = l3[c];
      d1 += xa1[4 * c + 0] * v1.x + xa1[4 * c + 1] * v1.y + xa1[4 * c + 2] * v1.z + xa1[4 * c + 3] * v1.w;
      d3 += xa3[4 * c + 0] * v3.x + xa3[4 * c + 1] * v3.y + xa3[4 * c + 2] * v3.z + xa3[4 * c + 3] * v3.w;
    }
    float h1 = hb1 + LSCALE * d1;
    float h3 = hb3 + LSCALE * d3;
    float s = h1 / (1.f + __expf(-h1));
    u16 ob = f2b(s * h3);
    if (ii < 8) o0[ii] = (short)ob; else o1[ii - 8] = (short)ob;
  }
  short8* dst = (short8*)(act + (size_t)pr * FDIM + f0 + fg);
  dst[0] = o0;
  dst[1] = o1;
}

// ---------------- ya2 = act @ a2[e]^T  (rank-16 reduce over F) ----------------
__global__ __launch_bounds__(256) void ya2_kernel(const u16* __restrict__ act, const float* __restrict__ a2,
                                                  const int* __restrict__ poff, float* __restrict__ ya2) {
  __shared__ float lact[16 * 68];
  __shared__ float la2[16 * 68];
  int r0 = blockIdx.x * 16;
  if (r0 >= poff[NEXP]) return;
  int e = 0;
  while (r0 >= poff[e + 1]) ++e;
  int p = threadIdx.x >> 4;
  int r = threadIdx.x & 15;
  int lrow = threadIdx.x >> 4;
  int c4 = (threadIdx.x & 15) << 2;
  float acc = 0.f;
  for (int f0 = 0; f0 < FDIM; f0 += 64) {
    __syncthreads();
    ushort4 av = *reinterpret_cast<const ushort4*>(act + (size_t)(r0 + lrow) * FDIM + f0 + c4);
    lact[lrow * 68 + c4 + 0] = b2f((short)av.x);
    lact[lrow * 68 + c4 + 1] = b2f((short)av.y);
    lact[lrow * 68 + c4 + 2] = b2f((short)av.z);
    lact[lrow * 68 + c4 + 3] = b2f((short)av.w);
    float4 bv = *reinterpret_cast<const float4*>(a2 + ((size_t)e * RLORA + lrow) * FDIM + f0 + c4);
    *reinterpret_cast<float4*>(la2 + lrow * 68 + c4) = bv;
    __syncthreads();
#pragma unroll
    for (int jj = 0; jj < 64; jj += 4) {
      float4 a4 = *reinterpret_cast<const float4*>(lact + p * 68 + jj);
      float4 b4 = *reinterpret_cast<const float4*>(la2 + r * 68 + jj);
      acc += a4.x * b4.x + a4.y * b4.y + a4.z * b4.z + a4.w * b4.w;
    }
  }
  ya2[(size_t)(r0 + p) * RLORA + r] = acc;
}

// ---------------- grouped down GEMM + LoRA + routing-weight epilogue ----------------
__global__ __launch_bounds__(512, 2) void gemm_down(const u16* __restrict__ act, const u16* __restrict__ w2b,
                                                    const float* __restrict__ b2, const float* __restrict__ ya2,
                                                    const int* __restrict__ pair_tok, const int* __restrict__ pair_k,
                                                    const float* __restrict__ pair_w, const int* __restrict__ poff,
                                                    float* __restrict__ slots) {
  // grid 1024 = 8 ntiles x (8 experts x 16 mtile slots); bijective XCD swizzle
  int orig = blockIdx.x;
  int wgid = (orig & 7) * 128 + (orig >> 3);
  int nt = wgid & 7, mslot = wgid >> 3;
  int e = mslot >> 4, mt = mslot & 15;
  int m0 = poff[e] + mt * 256;
  if (m0 >= poff[e + 1]) return;
  int n0 = nt * 256;
  __shared__ u16 lA[2 * 2 * 256 * 32];
  __shared__ u16 lB[2 * 2 * 256 * 32];
  f32x4 acc[8][4];
  f32x4 z = {0.f, 0.f, 0.f, 0.f};
#pragma unroll
  for (int i = 0; i < 8; ++i)
#pragma unroll
    for (int j = 0; j < 4; ++j) acc[i][j] = z;
  mm256(act + (size_t)m0 * FDIM, w2b + (size_t)n0 * FDIM, FDIM, FDIM, FDIM / 64,
        (char*)lA, (char*)lB, acc);
  const int tid = threadIdx.x;
  const int lane = tid & 63, wid = tid >> 6;
  const int wr = wid >> 2, wc = wid & 3;
  const int lm = lane & 15, lq = (lane >> 4) << 2;
#pragma unroll
  for (int n = 0; n < 4; ++n) {
    int col = n0 + wc * 64 + n * 16 + lm;
    const float* b2p = b2 + ((size_t)e * DDIM + col) * RLORA;
    float b2v[16];
#pragma unroll
    for (int rr = 0; rr < 16; ++rr) b2v[rr] = b2p[rr];
#pragma unroll
    for (int m = 0; m < 8; ++m) {
#pragma unroll
      for (int q = 0; q < 4; ++q) {
        int pidx = m0 + wr * 128 + m * 16 + lq + q;
        int tok = pair_tok[pidx];
        if (tok < 0) continue;
        const float* yr = ya2 + (size_t)pidx * RLORA;
        float dot = 0.f;
#pragma unroll
        for (int rr = 0; rr < 16; ++rr) dot += yr[rr] * b2v[rr];
        float val = (acc[m][n][q] + LSCALE * dot) * pair_w[pidx];
        slots[((size_t)tok * 2 + pair_k[pidx]) * DDIM + col] = val;
      }
    }
  }
}

// ---------------- combine the two expert slots per token ----------------
__global__ __launch_bounds__(256) void combine_kernel(const float4* __restrict__ slots, float4* __restrict__ out) {
  const int n4 = NTOK * (DDIM / 4);
  int stride = gridDim.x * 256;
  for (int i = blockIdx.x * 256 + threadIdx.x; i < n4; i += stride) {
    int tok = i >> 9;          // DDIM/4 = 512
    int c = i & 511;
    float4 v0 = slots[(size_t)(tok * 2) * 512 + c];
    float4 v1 = slots[(size_t)(tok * 2 + 1) * 512 + c];
    float4 o;
    o.x = v0.x + v1.x; o.y = v0.y + v1.y; o.z = v0.z + v1.z; o.w = v0.w + v1.w;
    out[i] = o;
  }
}

extern "C" void kernel_launch(void* const* d_in, const int* in_sizes, int n_in,
                              void* d_out, int out_size, void* d_ws, size_t ws_size,
                              hipStream_t stream) {
  (void)in_sizes; (void)n_in; (void)out_size; (void)ws_size;
  const float* x  = (const float*)d_in[0];
  const float* gw = (const float*)d_in[1];
  const float* w1 = (const float*)d_in[2];
  const float* w3 = (const float*)d_in[3];
  const float* w2 = (const float*)d_in[4];
  const float* a1 = (const float*)d_in[5];
  const float* b1 = (const float*)d_in[6];
  const float* a3 = (const float*)d_in[7];
  const float* b3 = (const float*)d_in[8];
  const float* a2 = (const float*)d_in[9];
  const float* b2 = (const float*)d_in[10];
  float* out = (float*)d_out;

  char* ws = (char*)d_ws;
  size_t off = 0;
  auto take = [&](size_t bytes) -> char* {
    char* p = ws + off;
    off += (bytes + 255) & ~(size_t)255;
    return p;
  };
  // region 1: base13 (94.4 MB) -> later reused by slots (67.1) + ya2 (0.66)
  char* reg1 = take((size_t)NTOK * BCOLS * 2);
  u16* base13 = (u16*)reg1;
  float* slots = (float*)reg1;
  float* ya2 = (float*)(reg1 + (size_t)NTOK * 2 * DDIM * 4);
  // region 2: act (115.3 MB); xb (16.8) + Ball (47.2) overlap its head (dead after gemm_base)
  char* reg2 = take((size_t)PADROWS * FDIM * 2);
  u16* actb = (u16*)reg2;
  u16* xb = (u16*)reg2;
  u16* Ball = (u16*)(reg2 + (size_t)NTOK * DDIM * 2);
  // region 3: w2b + small arrays
  u16* w2b = (u16*)take((size_t)DDIM * FDIM * 2);
  int2* tok_e   = (int2*)take((size_t)NTOK * 8);
  float2* tok_w = (float2*)take((size_t)NTOK * 8);
  int* pair_tok = (int*)take((size_t)PADROWS * 4);
  float* pair_w = (float*)take((size_t)PADROWS * 4);
  int* pair_k   = (int*)take((size_t)PADROWS * 4);
  int* poff     = (int*)take(256);

  cast_kernel<<<1024, 256, 0, stream>>>(w1, Ball, FDIM * DDIM / 4);
  cast_kernel<<<1024, 256, 0, stream>>>(w3, Ball + (size_t)FDIM * DDIM, FDIM * DDIM / 4);
  cast_kernel<<<64, 256, 0, stream>>>(a1, Ball + (size_t)TWOF * DDIM, NEXP * RLORA * DDIM / 4);
  cast_kernel<<<64, 256, 0, stream>>>(a3, Ball + (size_t)(TWOF + NEXP * RLORA) * DDIM, NEXP * RLORA * DDIM / 4);
  cast_kernel<<<1024, 256, 0, stream>>>(x, xb, NTOK * DDIM / 4);
  cast_kernel<<<1024, 256, 0, stream>>>(w2, w2b, DDIM * FDIM / 4);
  router_kernel<<<NTOK, 256, 0, stream>>>(x, gw, tok_e, tok_w);
  build_pairs<<<1, 256, 0, stream>>>(tok_e, tok_w, pair_tok, pair_w, pair_k, poff);
  gemm_base<<<720, 512, 0, stream>>>(xb, Ball, base13);
  dim3 g3(FDIM / 128, PADROWS / 32);
  act_kernel<<<g3, 256, 0, stream>>>(base13, b1, b3, pair_tok, poff, actb);
  ya2_kernel<<<PADROWS / 16, 256, 0, stream>>>(actb, a2, poff, ya2);
  gemm_down<<<1024, 512, 0, stream>>>(actb, w2b, b2, ya2, pair_tok, pair_k, pair_w, poff, slots);
  combine_kernel<<<2048, 256, 0, stream>>>((const float4*)slots, (float4*)out);
}

// Round 3
// 1110.432 us; speedup vs baseline: 1.0276x; 1.0276x over previous
//
#include <hip/hip_runtime.h>
#include <stdint.h>

#define NTOK 4096
#define DDIM 2048
#define FDIM 5632
#define NEXP 8
#define RLORA 16
#define TWOF 11264
#define BCOLS 11520   // 2F + 2*E*R  (w1 | w3 | a1 | a3 rows)
#define PADROWS 10240 // 8192 pairs + worst-case 8*255 padding, 256-granular
#define LSCALE 2.0f

typedef __attribute__((ext_vector_type(4))) float f32x4;
typedef __attribute__((ext_vector_type(8))) short short8;
typedef unsigned short u16;

#define AS1 __attribute__((address_space(1)))
#define AS3 __attribute__((address_space(3)))

__device__ __forceinline__ float b2f(short s) {
  union { float f; unsigned u; } v;
  v.u = ((unsigned)(u16)s) << 16;
  return v.f;
}
__device__ __forceinline__ u16 f2b(float f) {
  union { float f; unsigned u; } v; v.f = f;
  unsigned r = v.u + 0x7fffu + ((v.u >> 16) & 1u);   // RNE bf16
  return (u16)(r >> 16);
}

// ---------------- cast f32 -> bf16, 4-wide ----------------
__global__ __launch_bounds__(256) void cast_kernel(const float* __restrict__ src, u16* __restrict__ dst, int n4) {
  int stride = gridDim.x * 256;
  for (int i = blockIdx.x * 256 + threadIdx.x; i < n4; i += stride) {
    float4 v = reinterpret_cast<const float4*>(src)[i];
    ushort4 o;
    o.x = f2b(v.x); o.y = f2b(v.y); o.z = f2b(v.z); o.w = f2b(v.w);
    reinterpret_cast<ushort4*>(dst)[i] = o;
  }
}

// ---------------- router: fp32 logits, top-2, softmax ----------------
__global__ __launch_bounds__(256) void router_kernel(const float* __restrict__ x, const float* __restrict__ gw,
                                                     int2* __restrict__ tok_e, float2* __restrict__ tok_w) {
  int tok = blockIdx.x;
  const float* xr = x + (size_t)tok * DDIM;
  float acc[NEXP];
#pragma unroll
  for (int e = 0; e < NEXP; ++e) acc[e] = 0.f;
  for (int d = threadIdx.x; d < DDIM; d += 256) {
    float xv = xr[d];
#pragma unroll
    for (int e = 0; e < NEXP; ++e) acc[e] += xv * gw[e * DDIM + d];
  }
#pragma unroll
  for (int e = 0; e < NEXP; ++e) {
#pragma unroll
    for (int off = 32; off > 0; off >>= 1) acc[e] += __shfl_down(acc[e], off);
  }
  __shared__ float red[4][NEXP];
  int wid = threadIdx.x >> 6;
  int lane = threadIdx.x & 63;
  if (lane == 0) {
#pragma unroll
    for (int e = 0; e < NEXP; ++e) red[wid][e] = acc[e];
  }
  __syncthreads();
  if (threadIdx.x == 0) {
    float l[NEXP];
#pragma unroll
    for (int e = 0; e < NEXP; ++e) l[e] = red[0][e] + red[1][e] + red[2][e] + red[3][e];
    int i0 = 0;
#pragma unroll
    for (int e = 1; e < NEXP; ++e) if (l[e] > l[i0]) i0 = e;   // strict >: first max (top_k tie rule)
    int i1 = (i0 == 0) ? 1 : 0;
#pragma unroll
    for (int e = 0; e < NEXP; ++e) if (e != i0 && e != i1 && l[e] > l[i1]) i1 = e;
    float ex = __expf(l[i1] - l[i0]);       // <= 1
    float w0 = 1.f / (1.f + ex);
    float w1v = ex / (1.f + ex);
    int2 ev; ev.x = i0; ev.y = i1;
    float2 wv; wv.x = w0; wv.y = w1v;
    tok_e[tok] = ev;
    tok_w[tok] = wv;
  }
}

// ---------------- bucket (token,slot) pairs by expert, 256-padded ----------------
__global__ __launch_bounds__(256) void build_pairs(const int2* __restrict__ tok_e, const float2* __restrict__ tok_w,
                                                   int* __restrict__ pair_tok, float* __restrict__ pair_w,
                                                   int* __restrict__ pair_k, int* __restrict__ poff) {
  __shared__ int cnt[NEXP];
  __shared__ int base[NEXP + 1];
  __shared__ int cur[NEXP];
  if (threadIdx.x < NEXP) cnt[threadIdx.x] = 0;
  __syncthreads();
  for (int t = threadIdx.x; t < NTOK; t += 256) {
    int2 ee = tok_e[t];
    atomicAdd(&cnt[ee.x], 1);
    atomicAdd(&cnt[ee.y], 1);
  }
  for (int i = threadIdx.x; i < PADROWS; i += 256) pair_tok[i] = -1;
  __syncthreads();
  if (threadIdx.x == 0) {
    int o = 0;
#pragma unroll
    for (int e = 0; e < NEXP; ++e) { base[e] = o; o += ((cnt[e] + 255) >> 8) << 8; }
    base[NEXP] = o;
  }
  __syncthreads();
  if (threadIdx.x < NEXP) cur[threadIdx.x] = base[threadIdx.x];
  __syncthreads();
  for (int t = threadIdx.x; t < NTOK; t += 256) {
    int2 ee = tok_e[t];
    float2 wv = tok_w[t];
    int s0 = atomicAdd(&cur[ee.x], 1);
    pair_tok[s0] = t; pair_w[s0] = wv.x; pair_k[s0] = 0;
    int s1 = atomicAdd(&cur[ee.y], 1);
    pair_tok[s1] = t; pair_w[s1] = wv.y; pair_k[s1] = 1;
  }
  __syncthreads();
  if (threadIdx.x <= NEXP) poff[threadIdx.x] = base[threadIdx.x];
}

// ================= 256x256 8-phase bf16 MFMA GEMM (T2+T3/T4/T5) =================
// C = A(row-major [M][K]) * B(row-major [N][K])^T, 512 threads = 8 waves (2Mx4N),
// per-wave output 128x64 = acc[8][4]. LDS: [2 buf][2 khalf][256 rows][32 k] bf16 per
// operand = 128 KiB total.
// T2 bank swizzle: 16B slot within each 64B row is XORed with ((row>>1)&3).
// global_load_lds dest stays LINEAR; the global SOURCE column is pre-swizzled with
// the same involution; ds_read applies it on the read address (lane-constant).
// Verified: lanes 0-7 hit bank bases {0,16,4,20,8,24,12,28} -> all 32 banks.

__device__ __forceinline__ void stage_unit(const u16* __restrict__ src, int ld, char* ldsbase, int tid) {
#pragma unroll
  for (int h = 0; h < 2; ++h) {
    int q = h * 512 + tid;            // 0..1023 16B chunks; 256 rows x 4 slots
    int r = q >> 2, g = q & 3;
    int gs = g ^ ((r >> 1) & 3);      // inverse-swizzled source slot
    const char* s = (const char*)(src + (size_t)r * ld) + gs * 16;
    __builtin_amdgcn_global_load_lds((const AS1 void*)s, (AS3 void*)(ldsbase + q * 16), 16, 0, 0);
  }
}

#define GBAR()  { __builtin_amdgcn_s_barrier(); __builtin_amdgcn_sched_barrier(0); }

template<bool STG>
__device__ __forceinline__ void group4(const u16* __restrict__ An, const u16* __restrict__ Bn,
                                       int lda, int ldb,
                                       const char* Ard, const char* Brd, char* Awr, char* Bwr,
                                       int abase, int bbase, int tid, f32x4 (&acc)[8][4]) {
  short8 av[4], bv[4];
  // ---- phase 1: kh0, m-frags 0-3 + B n-frags 0-3; stage next B-kh0 ----
#pragma unroll
  for (int i = 0; i < 4; ++i) {
    av[i] = *(const short8*)(Ard + abase + i * 1024);
    bv[i] = *(const short8*)(Brd + bbase + i * 1024);
  }
  if (STG) stage_unit(Bn, ldb, Bwr, tid);
  GBAR();
  __builtin_amdgcn_s_setprio(1);
#pragma unroll
  for (int i = 0; i < 4; ++i)
#pragma unroll
    for (int j = 0; j < 4; ++j)
      acc[i][j] = __builtin_amdgcn_mfma_f32_16x16x32_bf16(av[i], bv[j], acc[i][j], 0, 0, 0);
  __builtin_amdgcn_s_setprio(0);
  GBAR();
  // ---- phase 2: kh0, m-frags 4-7 (reuse bv); stage next A-kh0; counted vmcnt ----
#pragma unroll
  for (int i = 0; i < 4; ++i)
    av[i] = *(const short8*)(Ard + abase + 4096 + i * 1024);
  if (STG) {
    stage_unit(An, lda, Awr, tid);
    asm volatile("s_waitcnt vmcnt(4)" ::: "memory");
    __builtin_amdgcn_sched_barrier(0);
  }
  GBAR();
  __builtin_amdgcn_s_setprio(1);
#pragma unroll
  for (int i = 0; i < 4; ++i)
#pragma unroll
    for (int j = 0; j < 4; ++j)
      acc[4 + i][j] = __builtin_amdgcn_mfma_f32_16x16x32_bf16(av[i], bv[j], acc[4 + i][j], 0, 0, 0);
  __builtin_amdgcn_s_setprio(0);
  GBAR();
  // ---- phase 3: kh1, m-frags 0-3 + B n-frags 0-3; stage next B-kh1 ----
#pragma unroll
  for (int i = 0; i < 4; ++i) {
    av[i] = *(const short8*)(Ard + 16384 + abase + i * 1024);
    bv[i] = *(const short8*)(Brd + 16384 + bbase + i * 1024);
  }
  if (STG) stage_unit(Bn + 32, ldb, Bwr + 16384, tid);
  GBAR();
  __builtin_amdgcn_s_setprio(1);
#pragma unroll
  for (int i = 0; i < 4; ++i)
#pragma unroll
    for (int j = 0; j < 4; ++j)
      acc[i][j] = __builtin_amdgcn_mfma_f32_16x16x32_bf16(av[i], bv[j], acc[i][j], 0, 0, 0);
  __builtin_amdgcn_s_setprio(0);
  GBAR();
  // ---- phase 4: kh1, m-frags 4-7; stage next A-kh1; counted vmcnt ----
#pragma unroll
  for (int i = 0; i < 4; ++i)
    av[i] = *(const short8*)(Ard + 16384 + abase + 4096 + i * 1024);
  if (STG) {
    stage_unit(An + 32, lda, Awr + 16384, tid);
    asm volatile("s_waitcnt vmcnt(4)" ::: "memory");
    __builtin_amdgcn_sched_barrier(0);
  }
  GBAR();
  __builtin_amdgcn_s_setprio(1);
#pragma unroll
  for (int i = 0; i < 4; ++i)
#pragma unroll
    for (int j = 0; j < 4; ++j)
      acc[4 + i][j] = __builtin_amdgcn_mfma_f32_16x16x32_bf16(av[i], bv[j], acc[4 + i][j], 0, 0, 0);
  __builtin_amdgcn_s_setprio(0);
  GBAR();
}

__device__ __forceinline__ void mm256(const u16* __restrict__ A, const u16* __restrict__ B,
                                      int lda, int ldb, int NT,
                                      char* lAb, char* lBb, f32x4 (&acc)[8][4]) {
  const int tid = threadIdx.x;
  const int lane = tid & 63, wid = tid >> 6;
  const int wr = wid >> 2, wc = wid & 3;
  const int lm = lane & 15, lg = lane >> 4;
  const int sw = lg ^ ((lm >> 1) & 3);                   // T2 read-side swizzle (lane-constant)
  const int abase = wr * 128 * 64 + lm * 64 + sw * 16;   // byte offset of m-frag 0 within khalf
  const int bbase = wc * 64 * 64 + lm * 64 + sw * 16;
  // prologue: stage tile 0 (4 units) into buf 0, drain fully
  stage_unit(B, ldb, lBb, tid);
  stage_unit(A, lda, lAb, tid);
  stage_unit(B + 32, ldb, lBb + 16384, tid);
  stage_unit(A + 32, lda, lAb + 16384, tid);
  asm volatile("s_waitcnt vmcnt(0)" ::: "memory");
  GBAR();
  for (int t = 0; t < NT - 1; ++t) {
    int c = t & 1;
    group4<true>(A + (size_t)(t + 1) * 64, B + (size_t)(t + 1) * 64, lda, ldb,
                 (const char*)(lAb + c * 32768), (const char*)(lBb + c * 32768),
                 lAb + (c ^ 1) * 32768, lBb + (c ^ 1) * 32768, abase, bbase, tid, acc);
  }
  asm volatile("s_waitcnt vmcnt(0)" ::: "memory");
  GBAR();
  int c = (NT - 1) & 1;
  group4<false>(A, B, lda, ldb,
                (const char*)(lAb + c * 32768), (const char*)(lBb + c * 32768),
                lAb, lBb, abase, bbase, tid, acc);
}

// ---------------- GEMM1: base13_ext = x_bf16 @ [w1;w3;a1;a3]^T ----------------
__global__ __launch_bounds__(512, 2) void gemm_base(const u16* __restrict__ xb, const u16* __restrict__ Ball,
                                                    u16* __restrict__ base13) {
  __shared__ u16 lA[2 * 2 * 256 * 32];
  __shared__ u16 lB[2 * 2 * 256 * 32];
  // bijective XCD swizzle: nwg = 720 = 8*90
  int orig = blockIdx.x;
  int wgid = (orig & 7) * 90 + (orig >> 3);
  int mt = wgid / 45, nt = wgid % 45;
  int m0 = mt * 256, n0 = nt * 256;
  f32x4 acc[8][4];
  f32x4 z = {0.f, 0.f, 0.f, 0.f};
#pragma unroll
  for (int i = 0; i < 8; ++i)
#pragma unroll
    for (int j = 0; j < 4; ++j) acc[i][j] = z;
  mm256(xb + (size_t)m0 * DDIM, Ball + (size_t)n0 * DDIM, DDIM, DDIM, DDIM / 64,
        (char*)lA, (char*)lB, acc);
  const int tid = threadIdx.x;
  const int lane = tid & 63, wid = tid >> 6;
  const int wr = wid >> 2, wc = wid & 3;
  const int lm = lane & 15, lq = (lane >> 4) << 2;
#pragma unroll
  for (int m = 0; m < 8; ++m) {
#pragma unroll
    for (int n = 0; n < 4; ++n) {
      int col = n0 + wc * 64 + n * 16 + lm;
#pragma unroll
      for (int q = 0; q < 4; ++q) {
        int row = m0 + wr * 128 + m * 16 + lq + q;
        base13[(size_t)row * BCOLS + col] = f2b(acc[m][n][q]);
      }
    }
  }
}

// ---------------- act: SwiGLU with rank-16 LoRA on h1/h3 ----------------
__global__ __launch_bounds__(256) void act_kernel(const u16* __restrict__ base13,
                                                  const float* __restrict__ b1, const float* __restrict__ b3,
                                                  const int* __restrict__ pair_tok, const int* __restrict__ poff,
                                                  u16* __restrict__ act) {
  __shared__ float lb1[128 * 16];
  __shared__ float lb3[128 * 16];
  int f0 = blockIdx.x * 128;
  int r0 = blockIdx.y * 32;
  if (r0 >= poff[NEXP]) return;
  int e = 0;
  while (r0 >= poff[e + 1]) ++e;
  const float4* pb1 = reinterpret_cast<const float4*>(b1 + ((size_t)e * FDIM + f0) * RLORA);
  const float4* pb3 = reinterpret_cast<const float4*>(b3 + ((size_t)e * FDIM + f0) * RLORA);
  for (int i = threadIdx.x; i < 128 * 16 / 4; i += 256) {
    reinterpret_cast<float4*>(lb1)[i] = pb1[i];
    reinterpret_cast<float4*>(lb3)[i] = pb3[i];
  }
  __syncthreads();
  int pr = r0 + (threadIdx.x >> 3);
  int fg = (threadIdx.x & 7) << 4;
  int tok = pair_tok[pr];
  if (tok < 0) return;
  const u16* bp = base13 + (size_t)tok * BCOLS;
  short8 x1a = *(const short8*)(bp + TWOF + e * 16);
  short8 x1b = *(const short8*)(bp + TWOF + e * 16 + 8);
  short8 x3a = *(const short8*)(bp + TWOF + NEXP * RLORA + e * 16);
  short8 x3b = *(const short8*)(bp + TWOF + NEXP * RLORA + e * 16 + 8);
  float xa1[16], xa3[16];
#pragma unroll
  for (int r = 0; r < 8; ++r) {
    xa1[r] = b2f(x1a[r]); xa1[r + 8] = b2f(x1b[r]);
    xa3[r] = b2f(x3a[r]); xa3[r + 8] = b2f(x3b[r]);
  }
  short8 h1a = *(const short8*)(bp + f0 + fg);
  short8 h1b = *(const short8*)(bp + f0 + fg + 8);
  short8 h3a = *(const short8*)(bp + FDIM + f0 + fg);
  short8 h3b = *(const short8*)(bp + FDIM + f0 + fg + 8);
  short8 o0, o1;
#pragma unroll
  for (int ii = 0; ii < 16; ++ii) {
    float hb1 = b2f(ii < 8 ? h1a[ii] : h1b[ii - 8]);
    float hb3 = b2f(ii < 8 ? h3a[ii] : h3b[ii - 8]);
    const float4* l1 = reinterpret_cast<const float4*>(lb1 + (fg + ii) * 16);
    const float4* l3 = reinterpret_cast<const float4*>(lb3 + (fg + ii) * 16);
    float d1 = 0.f, d3 = 0.f;
#pragma unroll
    for (int c = 0; c < 4; ++c) {
      float4 v1 = l1[c], v3 = l3[c];
      d1 += xa1[4 * c + 0] * v1.x + xa1[4 * c + 1] * v1.y + xa1[4 * c + 2] * v1.z + xa1[4 * c + 3] * v1.w;
      d3 += xa3[4 * c + 0] * v3.x + xa3[4 * c + 1] * v3.y + xa3[4 * c + 2] * v3.z + xa3[4 * c + 3] * v3.w;
    }
    float h1 = hb1 + LSCALE * d1;
    float h3 = hb3 + LSCALE * d3;
    float s = h1 / (1.f + __expf(-h1));
    u16 ob = f2b(s * h3);
    if (ii < 8) o0[ii] = (short)ob; else o1[ii - 8] = (short)ob;
  }
  short8* dst = (short8*)(act + (size_t)pr * FDIM + f0 + fg);
  dst[0] = o0;
  dst[1] = o1;
}

// ---------------- ya2 = act @ a2[e]^T  (rank-16 reduce over F) ----------------
__global__ __launch_bounds__(256) void ya2_kernel(const u16* __restrict__ act, const float* __restrict__ a2,
                                                  const int* __restrict__ poff, float* __restrict__ ya2) {
  __shared__ float lact[16 * 68];
  __shared__ float la2[16 * 68];
  int r0 = blockIdx.x * 16;
  if (r0 >= poff[NEXP]) return;
  int e = 0;
  while (r0 >= poff[e + 1]) ++e;
  int p = threadIdx.x >> 4;
  int r = threadIdx.x & 15;
  int lrow = threadIdx.x >> 4;
  int c4 = (threadIdx.x & 15) << 2;
  float acc = 0.f;
  for (int f0 = 0; f0 < FDIM; f0 += 64) {
    __syncthreads();
    ushort4 av = *reinterpret_cast<const ushort4*>(act + (size_t)(r0 + lrow) * FDIM + f0 + c4);
    lact[lrow * 68 + c4 + 0] = b2f((short)av.x);
    lact[lrow * 68 + c4 + 1] = b2f((short)av.y);
    lact[lrow * 68 + c4 + 2] = b2f((short)av.z);
    lact[lrow * 68 + c4 + 3] = b2f((short)av.w);
    float4 bv = *reinterpret_cast<const float4*>(a2 + ((size_t)e * RLORA + lrow) * FDIM + f0 + c4);
    *reinterpret_cast<float4*>(la2 + lrow * 68 + c4) = bv;
    __syncthreads();
#pragma unroll
    for (int jj = 0; jj < 64; jj += 4) {
      float4 a4 = *reinterpret_cast<const float4*>(lact + p * 68 + jj);
      float4 b4 = *reinterpret_cast<const float4*>(la2 + r * 68 + jj);
      acc += a4.x * b4.x + a4.y * b4.y + a4.z * b4.z + a4.w * b4.w;
    }
  }
  ya2[(size_t)(r0 + p) * RLORA + r] = acc;
}

// ---------------- grouped down GEMM + LoRA + routing-weight epilogue ----------------
__global__ __launch_bounds__(512, 2) void gemm_down(const u16* __restrict__ act, const u16* __restrict__ w2b,
                                                    const float* __restrict__ b2, const float* __restrict__ ya2,
                                                    const int* __restrict__ pair_tok, const int* __restrict__ pair_k,
                                                    const float* __restrict__ pair_w, const int* __restrict__ poff,
                                                    float* __restrict__ slots) {
  // grid 1024 = 8 ntiles x (8 experts x 16 mtile slots); bijective XCD swizzle
  int orig = blockIdx.x;
  int wgid = (orig & 7) * 128 + (orig >> 3);
  int nt = wgid & 7, mslot = wgid >> 3;
  int e = mslot >> 4, mt = mslot & 15;
  int m0 = poff[e] + mt * 256;
  if (m0 >= poff[e + 1]) return;
  int n0 = nt * 256;
  __shared__ u16 lA[2 * 2 * 256 * 32];
  __shared__ u16 lB[2 * 2 * 256 * 32];
  f32x4 acc[8][4];
  f32x4 z = {0.f, 0.f, 0.f, 0.f};
#pragma unroll
  for (int i = 0; i < 8; ++i)
#pragma unroll
    for (int j = 0; j < 4; ++j) acc[i][j] = z;
  mm256(act + (size_t)m0 * FDIM, w2b + (size_t)n0 * FDIM, FDIM, FDIM, FDIM / 64,
        (char*)lA, (char*)lB, acc);
  const int tid = threadIdx.x;
  const int lane = tid & 63, wid = tid >> 6;
  const int wr = wid >> 2, wc = wid & 3;
  const int lm = lane & 15, lq = (lane >> 4) << 2;
#pragma unroll
  for (int n = 0; n < 4; ++n) {
    int col = n0 + wc * 64 + n * 16 + lm;
    const float* b2p = b2 + ((size_t)e * DDIM + col) * RLORA;
    float b2v[16];
#pragma unroll
    for (int rr = 0; rr < 16; ++rr) b2v[rr] = b2p[rr];
#pragma unroll
    for (int m = 0; m < 8; ++m) {
#pragma unroll
      for (int q = 0; q < 4; ++q) {
        int pidx = m0 + wr * 128 + m * 16 + lq + q;
        int tok = pair_tok[pidx];
        if (tok < 0) continue;
        const float* yr = ya2 + (size_t)pidx * RLORA;
        float dot = 0.f;
#pragma unroll
        for (int rr = 0; rr < 16; ++rr) dot += yr[rr] * b2v[rr];
        float val = (acc[m][n][q] + LSCALE * dot) * pair_w[pidx];
        slots[((size_t)tok * 2 + pair_k[pidx]) * DDIM + col] = val;
      }
    }
  }
}

// ---------------- combine the two expert slots per token ----------------
__global__ __launch_bounds__(256) void combine_kernel(const float4* __restrict__ slots, float4* __restrict__ out) {
  const int n4 = NTOK * (DDIM / 4);
  int stride = gridDim.x * 256;
  for (int i = blockIdx.x * 256 + threadIdx.x; i < n4; i += stride) {
    int tok = i >> 9;          // DDIM/4 = 512
    int c = i & 511;
    float4 v0 = slots[(size_t)(tok * 2) * 512 + c];
    float4 v1 = slots[(size_t)(tok * 2 + 1) * 512 + c];
    float4 o;
    o.x = v0.x + v1.x; o.y = v0.y + v1.y; o.z = v0.z + v1.z; o.w = v0.w + v1.w;
    out[i] = o;
  }
}

extern "C" void kernel_launch(void* const* d_in, const int* in_sizes, int n_in,
                              void* d_out, int out_size, void* d_ws, size_t ws_size,
                              hipStream_t stream) {
  (void)in_sizes; (void)n_in; (void)out_size; (void)ws_size;
  const float* x  = (const float*)d_in[0];
  const float* gw = (const float*)d_in[1];
  const float* w1 = (const float*)d_in[2];
  const float* w3 = (const float*)d_in[3];
  const float* w2 = (const float*)d_in[4];
  const float* a1 = (const float*)d_in[5];
  const float* b1 = (const float*)d_in[6];
  const float* a3 = (const float*)d_in[7];
  const float* b3 = (const float*)d_in[8];
  const float* a2 = (const float*)d_in[9];
  const float* b2 = (const float*)d_in[10];
  float* out = (float*)d_out;

  char* ws = (char*)d_ws;
  size_t off = 0;
  auto take = [&](size_t bytes) -> char* {
    char* p = ws + off;
    off += (bytes + 255) & ~(size_t)255;
    return p;
  };
  // region 1: base13 (94.4 MB) -> later reused by slots (67.1) + ya2 (0.66)
  char* reg1 = take((size_t)NTOK * BCOLS * 2);
  u16* base13 = (u16*)reg1;
  float* slots = (float*)reg1;
  float* ya2 = (float*)(reg1 + (size_t)NTOK * 2 * DDIM * 4);
  // region 2: act (115.3 MB); xb (16.8) + Ball (47.2) overlap its head (dead after gemm_base)
  char* reg2 = take((size_t)PADROWS * FDIM * 2);
  u16* actb = (u16*)reg2;
  u16* xb = (u16*)reg2;
  u16* Ball = (u16*)(reg2 + (size_t)NTOK * DDIM * 2);
  // region 3: w2b + small arrays
  u16* w2b = (u16*)take((size_t)DDIM * FDIM * 2);
  int2* tok_e   = (int2*)take((size_t)NTOK * 8);
  float2* tok_w = (float2*)take((size_t)NTOK * 8);
  int* pair_tok = (int*)take((size_t)PADROWS * 4);
  float* pair_w = (float*)take((size_t)PADROWS * 4);
  int* pair_k   = (int*)take((size_t)PADROWS * 4);
  int* poff     = (int*)take(256);

  cast_kernel<<<1024, 256, 0, stream>>>(w1, Ball, FDIM * DDIM / 4);
  cast_kernel<<<1024, 256, 0, stream>>>(w3, Ball + (size_t)FDIM * DDIM, FDIM * DDIM / 4);
  cast_kernel<<<64, 256, 0, stream>>>(a1, Ball + (size_t)TWOF * DDIM, NEXP * RLORA * DDIM / 4);
  cast_kernel<<<64, 256, 0, stream>>>(a3, Ball + (size_t)(TWOF + NEXP * RLORA) * DDIM, NEXP * RLORA * DDIM / 4);
  cast_kernel<<<1024, 256, 0, stream>>>(x, xb, NTOK * DDIM / 4);
  cast_kernel<<<1024, 256, 0, stream>>>(w2, w2b, DDIM * FDIM / 4);
  router_kernel<<<NTOK, 256, 0, stream>>>(x, gw, tok_e, tok_w);
  build_pairs<<<1, 256, 0, stream>>>(tok_e, tok_w, pair_tok, pair_w, pair_k, poff);
  gemm_base<<<720, 512, 0, stream>>>(xb, Ball, base13);
  dim3 g3(FDIM / 128, PADROWS / 32);
  act_kernel<<<g3, 256, 0, stream>>>(base13, b1, b3, pair_tok, poff, actb);
  ya2_kernel<<<PADROWS / 16, 256, 0, stream>>>(actb, a2, poff, ya2);
  gemm_down<<<1024, 512, 0, stream>>>(actb, w2b, b2, ya2, pair_tok, pair_k, pair_w, poff, slots);
  combine_kernel<<<2048, 256, 0, stream>>>((const float4*)slots, (float4*)out);
}